// Round 5
// baseline (2312.771 us; speedup 1.0000x reference)
//
#include <hip/hip_runtime.h>
#include <stdint.h>

#define NB 8
#define NN 2048
#define HH 1024
#define FFD 4096
constexpr float EPS_ = 1e-5f;

typedef _Float16 f16;
typedef _Float16 f16x8 __attribute__((ext_vector_type(8)));
typedef float f32x4 __attribute__((ext_vector_type(4)));
typedef float f32x16 __attribute__((ext_vector_type(16)));

__device__ __forceinline__ f32x4 MFMA16(f16x8 a, f16x8 b, f32x4 c) {
  return __builtin_amdgcn_mfma_f32_16x16x32_f16(a, b, c, 0, 0, 0);
}
__device__ __forceinline__ f32x16 MFMA32(f16x8 a, f16x8 b, f32x16 c) {
  return __builtin_amdgcn_mfma_f32_32x32x16_f16(a, b, c, 0, 0, 0);
}
__device__ __forceinline__ ushort h2u(f16 h) { union { f16 h; ushort u; } v; v.h = h; return v.u; }
__device__ __forceinline__ unsigned pack2(float a, float b) {
  return (unsigned)h2u((f16)a) | ((unsigned)h2u((f16)b) << 16);
}
__device__ __forceinline__ float4 ld4(const float* p) { return *(const float4*)p; }
__device__ __forceinline__ float gelu(float u) {
  return 0.5f * u * (1.0f + erff(u * 0.70710678118654752f));
}
__device__ __forceinline__ void gload16(const void* g, void* l) {
  __builtin_amdgcn_global_load_lds(
      (const __attribute__((address_space(1))) unsigned int*)g,
      (__attribute__((address_space(3))) unsigned int*)l, 16, 0, 0);
}
// 8 consecutive fp32 -> f16x8
__device__ __forceinline__ f16x8 cvt8(const float* p) {
  float4 a = ld4(p), b = ld4(p + 4);
  union { unsigned u[4]; f16x8 v; } cv;
  cv.u[0] = pack2(a.x, a.y); cv.u[1] = pack2(a.z, a.w);
  cv.u[2] = pack2(b.x, b.y); cv.u[3] = pack2(b.z, b.w);
  return cv.v;
}

// ---------------- prep: x -> f16 hi/lo split ----------------
__global__ void convert_hl(const float* __restrict__ x, f16* __restrict__ xh,
                           f16* __restrict__ xl) {
  const size_t i = ((size_t)blockIdx.x * blockDim.x + threadIdx.x) * 4;
  float4 v = ld4(x + i);
  f16 h0 = (f16)v.x, h1 = (f16)v.y, h2 = (f16)v.z, h3 = (f16)v.w;
  ushort4 ho = {h2u(h0), h2u(h1), h2u(h2), h2u(h3)};
  ushort4 lo = {h2u((f16)(v.x - (float)h0)), h2u((f16)(v.y - (float)h1)),
                h2u((f16)(v.z - (float)h2)), h2u((f16)(v.w - (float)h3))};
  *(ushort4*)(xh + i) = ho;
  *(ushort4*)(xl + i) = lo;
}

// ---------------- prep: transpose fp32 -> f16, dst[C][R] = (f16)src[R][C] ----------------
__global__ void transpose_f16k(const float* __restrict__ src, f16* __restrict__ dst,
                               int R, int C, long sbs, long dbs) {
  __shared__ float tl[32][33];
  src += (size_t)blockIdx.z * sbs;
  dst += (size_t)blockIdx.z * dbs;
  const int t = threadIdx.x;
  const int c0 = blockIdx.x * 32, r0 = blockIdx.y * 32;
  {
    const int r = t >> 3, c4 = t & 7;
    float4 v = ld4(src + (size_t)(r0 + r) * C + c0 + c4 * 4);
    tl[r][c4 * 4 + 0] = v.x; tl[r][c4 * 4 + 1] = v.y;
    tl[r][c4 * 4 + 2] = v.z; tl[r][c4 * 4 + 3] = v.w;
  }
  __syncthreads();
  {
    const int c = t >> 3, r4 = t & 7;
    ushort4 o;
    o.x = h2u((f16)tl[r4 * 4 + 0][c]);
    o.y = h2u((f16)tl[r4 * 4 + 1][c]);
    o.z = h2u((f16)tl[r4 * 4 + 2][c]);
    o.w = h2u((f16)tl[r4 * 4 + 3][c]);
    *(ushort4*)(dst + (size_t)(c0 + c) * R + r0 + r4 * 4) = o;
  }
}

// ---------------- attn v2: flash, 512 thr / 8 waves, BM=64, 32x32x16 MFMA ----------------
#define RSTR 528
__device__ __forceinline__ void stageKB(char* REGb, const f16* xhb, const f16* xlb,
                                        int j0, int k0, int w, int l) {
#pragma unroll
  for (int r = 0; r < 2; ++r) {
    const int grp = r * 8 + w;
    const int j = grp * 16 + (l >> 2);
    const int clog = (l & 3) ^ ((j >> 1) & 3);
    const size_t src = (size_t)(j0 + j) * HH + k0 + clog * 8;
    gload16(xhb + src, REGb + grp * 1024);
    gload16(xlb + src, REGb + 16384 + grp * 1024);
  }
}
__device__ __forceinline__ void stageVB(char* VBb, const f16* xtb, int jabs, int w, int l) {
#pragma unroll
  for (int r = 0; r < 4; ++r) {
    const int grp = r * 8 + w;
    const int h = grp * 32 + (l >> 1);
    const int clog = (l & 1) ^ ((h >> 2) & 1);
    gload16(xtb + (size_t)h * NN + jabs + clog * 8, VBb + grp * 1024);
  }
}

template<bool WH>
__global__ __launch_bounds__(512, 2)
void attn_v2(const float* __restrict__ x, const f16* __restrict__ xh,
             const f16* __restrict__ xl, const f16* __restrict__ xt,
             const float* __restrict__ g1, const float* __restrict__ lb1,
             float* __restrict__ hout, f16* __restrict__ h16) {
  extern __shared__ char smem[];
  char* REG = smem;                         // 65536
  char* PB  = smem + 65536;                 // 33792
  float* RD   = (float*)(smem + 99328);     // [4][64]
  float* mrow = (float*)(smem + 100352);
  float* lrow = (float*)(smem + 100608);
  float* fctb = (float*)(smem + 100864);

  const int t = threadIdx.x, l = t & 63, w = t >> 6;
  const int l31 = l & 31, lh = l >> 5;
  const int wr = w >> 2, wc = w & 3;
  const int b = blockIdx.y, m0 = blockIdx.x * 64;
  const f16* __restrict__ xhb = xh + (size_t)b * NN * HH;
  const f16* __restrict__ xlb = xl + (size_t)b * NN * HH;
  const f16* __restrict__ xtb = xt + (size_t)b * HH * NN;
  const float* __restrict__ xb = x + (size_t)b * NN * HH;

  if (t < 64) { mrow[t] = -INFINITY; lrow[t] = 0.f; }

  f32x16 Oacc[8] = {};
  const int arow = m0 + wr * 32 + l31;

  for (int jt = 0; jt < 8; ++jt) {
    const int j0 = jt * 256;
    f32x16 sacc[2] = {};

    f16x8 ah[2], al[2];
#pragma unroll
    for (int s = 0; s < 2; ++s) {
      ah[s] = *(const f16x8*)(xhb + (size_t)arow * HH + s * 16 + lh * 8);
      al[s] = *(const f16x8*)(xlb + (size_t)arow * HH + s * 16 + lh * 8);
    }
    stageKB(REG, xhb, xlb, j0, 0, w, l);
    __syncthreads();
    int buf = 0;
    for (int kc = 0; kc < 32; ++kc) {
      f16x8 nh[2], nl[2];
      if (kc < 31) {
        stageKB(REG + (buf ^ 1) * 32768, xhb, xlb, j0, (kc + 1) * 32, w, l);
        const int kn = (kc + 1) * 32;
#pragma unroll
        for (int s = 0; s < 2; ++s) {
          nh[s] = *(const f16x8*)(xhb + (size_t)arow * HH + kn + s * 16 + lh * 8);
          nl[s] = *(const f16x8*)(xlb + (size_t)arow * HH + kn + s * 16 + lh * 8);
        }
      }
      const char* KH = REG + buf * 32768;
      const char* KL = KH + 16384;
#pragma unroll
      for (int ct = 0; ct < 2; ++ct) {
        const int j = wc * 64 + ct * 32 + l31;
        const int swz = (j >> 1) & 3;
        const char* rowH = KH + j * 64;
        const char* rowL = KL + j * 64;
#pragma unroll
        for (int s = 0; s < 2; ++s) {
          const int cp = (s * 2 + lh) ^ swz;
          f16x8 bh = *(const f16x8*)(rowH + cp * 16);
          f16x8 bl = *(const f16x8*)(rowL + cp * 16);
          sacc[ct] = MFMA32(ah[s], bh, sacc[ct]);
          sacc[ct] = MFMA32(al[s], bh, sacc[ct]);
          sacc[ct] = MFMA32(ah[s], bl, sacc[ct]);
        }
      }
      __syncthreads();
      if (kc < 31) {
#pragma unroll
        for (int s = 0; s < 2; ++s) { ah[s] = nh[s]; al[s] = nl[s]; }
      }
      buf ^= 1;
    }

    float tmax[16];
#pragma unroll
    for (int rg = 0; rg < 16; ++rg) tmax[rg] = fmaxf(sacc[0][rg], sacc[1][rg]);
#pragma unroll
    for (int off = 1; off <= 16; off <<= 1)
#pragma unroll
      for (int rg = 0; rg < 16; ++rg) tmax[rg] = fmaxf(tmax[rg], __shfl_xor(tmax[rg], off, 64));
    if (l31 == 0) {
#pragma unroll
      for (int rg = 0; rg < 16; ++rg) {
        const int rl = (rg & 3) + 8 * (rg >> 2) + 4 * lh;
        RD[wc * 64 + wr * 32 + rl] = tmax[rg];
      }
    }
    __syncthreads();
    if (t < 64) {
      float mt = fmaxf(fmaxf(RD[t], RD[64 + t]), fmaxf(RD[128 + t], RD[192 + t]));
      float mo = mrow[t];
      float mn = fmaxf(mo, mt);
      mrow[t] = mn;
      fctb[t] = __expf(mo - mn);
    }
    __syncthreads();
    float mv[16], psum[16];
#pragma unroll
    for (int rg = 0; rg < 16; ++rg)
      mv[rg] = mrow[wr * 32 + (rg & 3) + 8 * (rg >> 2) + 4 * lh];
#pragma unroll
    for (int ct = 0; ct < 2; ++ct) {
#pragma unroll
      for (int rg = 0; rg < 16; ++rg) {
        float p = __expf(sacc[ct][rg] - mv[rg]);
        if (ct == 0) psum[rg] = p; else psum[rg] += p;
        float po = __shfl_xor(p, 1, 64);
        if (!(l & 1)) {
          const int R = wr * 32 + (rg & 3) + 8 * (rg >> 2) + 4 * lh;
          const int col = wc * 64 + ct * 32 + l31;
          *(unsigned*)(PB + R * RSTR + col * 2) = pack2(p, po);
        }
      }
    }
#pragma unroll
    for (int off = 1; off <= 16; off <<= 1)
#pragma unroll
      for (int rg = 0; rg < 16; ++rg) psum[rg] += __shfl_xor(psum[rg], off, 64);
    if (l31 == 0) {
#pragma unroll
      for (int rg = 0; rg < 16; ++rg) {
        const int rl = (rg & 3) + 8 * (rg >> 2) + 4 * lh;
        RD[wc * 64 + wr * 32 + rl] = psum[rg];
      }
    }
    __syncthreads();
    if (t < 64) lrow[t] = lrow[t] * fctb[t] + (RD[t] + RD[64 + t] + RD[128 + t] + RD[192 + t]);
    float fv[16];
#pragma unroll
    for (int rg = 0; rg < 16; ++rg)
      fv[rg] = fctb[wr * 32 + (rg & 3) + 8 * (rg >> 2) + 4 * lh];
#pragma unroll
    for (int ht = 0; ht < 8; ++ht)
#pragma unroll
      for (int rg = 0; rg < 16; ++rg) Oacc[ht][rg] *= fv[rg];

    stageVB(REG, xtb, j0, w, l);
    __syncthreads();
    int vbuf = 0;
    for (int jc = 0; jc < 16; ++jc) {
      if (jc < 15) stageVB(REG + (vbuf ^ 1) * 32768, xtb, j0 + (jc + 1) * 16, w, l);
      const char* VBc = REG + vbuf * 32768;
      f16x8 pa = *(const f16x8*)(PB + (wr * 32 + l31) * RSTR + (jc * 2 + lh) * 16);
#pragma unroll
      for (int ht = 0; ht < 8; ++ht) {
        const int h = wc * 256 + ht * 32 + l31;
        f16x8 vb = *(const f16x8*)(VBc + h * 32 + ((lh ^ ((h >> 2) & 1)) * 16));
        Oacc[ht] = MFMA32(pa, vb, Oacc[ht]);
      }
      __syncthreads();
      vbuf ^= 1;
    }
  }

  float lv[16];
#pragma unroll
  for (int rg = 0; rg < 16; ++rg)
    lv[rg] = 1.0f / lrow[wr * 32 + (rg & 3) + 8 * (rg >> 2) + 4 * lh];
  float musum[16];
#pragma unroll
  for (int rg = 0; rg < 16; ++rg) musum[rg] = 0.f;
#pragma unroll
  for (int ht = 0; ht < 8; ++ht) {
    const int col = wc * 256 + ht * 32 + l31;
#pragma unroll
    for (int rg = 0; rg < 16; ++rg) {
      const int R = wr * 32 + (rg & 3) + 8 * (rg >> 2) + 4 * lh;
      float v = fmaf(Oacc[ht][rg], lv[rg], xb[(size_t)(m0 + R) * HH + col]);
      Oacc[ht][rg] = v; musum[rg] += v;
    }
  }
#pragma unroll
  for (int off = 1; off <= 16; off <<= 1)
#pragma unroll
    for (int rg = 0; rg < 16; ++rg) musum[rg] += __shfl_xor(musum[rg], off, 64);
  if (l31 == 0) {
#pragma unroll
    for (int rg = 0; rg < 16; ++rg) {
      const int rl = (rg & 3) + 8 * (rg >> 2) + 4 * lh;
      RD[wc * 64 + wr * 32 + rl] = musum[rg];
    }
  }
  __syncthreads();
  if (t < 64) mrow[t] = (RD[t] + RD[64 + t] + RD[128 + t] + RD[192 + t]) * (1.0f / HH);
  __syncthreads();
  float mu[16], vsum[16];
#pragma unroll
  for (int rg = 0; rg < 16; ++rg) {
    mu[rg] = mrow[wr * 32 + (rg & 3) + 8 * (rg >> 2) + 4 * lh];
    vsum[rg] = 0.f;
  }
#pragma unroll
  for (int ht = 0; ht < 8; ++ht)
#pragma unroll
    for (int rg = 0; rg < 16; ++rg) {
      float d = Oacc[ht][rg] - mu[rg];
      vsum[rg] += d * d;
    }
#pragma unroll
  for (int off = 1; off <= 16; off <<= 1)
#pragma unroll
    for (int rg = 0; rg < 16; ++rg) vsum[rg] += __shfl_xor(vsum[rg], off, 64);
  if (l31 == 0) {
#pragma unroll
    for (int rg = 0; rg < 16; ++rg) {
      const int rl = (rg & 3) + 8 * (rg >> 2) + 4 * lh;
      RD[wc * 64 + wr * 32 + rl] = vsum[rg];
    }
  }
  __syncthreads();
  if (t < 64) fctb[t] = rsqrtf((RD[t] + RD[64 + t] + RD[128 + t] + RD[192 + t]) * (1.0f / HH) + EPS_);
  __syncthreads();
  float rs[16];
#pragma unroll
  for (int rg = 0; rg < 16; ++rg)
    rs[rg] = fctb[wr * 32 + (rg & 3) + 8 * (rg >> 2) + 4 * lh];
#pragma unroll
  for (int ht = 0; ht < 8; ++ht) {
    const int col = wc * 256 + ht * 32 + l31;
    const float gv = g1[col], bv = lb1[col];
#pragma unroll
    for (int rg = 0; rg < 16; ++rg) {
      const int R = wr * 32 + (rg & 3) + 8 * (rg >> 2) + 4 * lh;
      const float ov = (Oacc[ht][rg] - mu[rg]) * rs[rg] * gv + bv;
      hout[((size_t)b * NN + m0 + R) * HH + col] = ov;
      if (WH) h16[((size_t)b * NN + m0 + R) * HH + col] = (f16)ov;
    }
  }
}

// ---------------- ffn v2: attn_v2-style, 1024 thr / 16 waves, BM=64 ----------------
// LDS: REG 64KB (mm1: W1[2][256f][64k] / mm2: W2[2][1024h][16f]) | GB g[64][256] swz | RD etc
__device__ __forceinline__ void stageW1(char* dst, const f16* w1t, int f0, int k0,
                                        int w, int l) {
#pragma unroll
  for (int r = 0; r < 2; ++r) {
    const int grp = r * 16 + w;               // 0..31, 8 rows each
    const int row = grp * 8 + (l >> 3);       // f index 0..255
    const int sl = (l & 7) ^ (row & 7);
    gload16(w1t + (size_t)(f0 + row) * HH + k0 + sl * 8, dst + grp * 1024);
  }
}
__device__ __forceinline__ void stageW2(char* dst, const f16* w2t, int fabs,
                                        int w, int l) {
#pragma unroll
  for (int r = 0; r < 2; ++r) {
    const int grp = r * 16 + w;               // 0..31, 32 rows each
    const int h = grp * 32 + (l >> 1);        // h index 0..1023
    const int clog = (l & 1) ^ ((h >> 2) & 1);
    gload16(w2t + (size_t)h * FFD + fabs + clog * 8, dst + grp * 1024);
  }
}

template<bool HF>
__global__ __launch_bounds__(1024)
void ffn_v2(float* __restrict__ hio, const f16* __restrict__ h16,
            const float* __restrict__ g2, const float* __restrict__ lb2,
            const float* __restrict__ b1f, const float* __restrict__ b2f,
            const f16* __restrict__ w1t, const f16* __restrict__ w2t) {
  extern __shared__ char smem[];
  char* REG = smem;                      // 65536
  char* GB  = smem + 65536;              // 32768: g[64][256] f16, 16B-slot swizzled
  float* RD  = (float*)(smem + 98304);   // [8][64]
  float* MUB = (float*)(smem + 100352);  // [64]
  float* RSB = (float*)(smem + 100608);  // [64]

  const int t = threadIdx.x, l = t & 63, w = t >> 6;
  const int l31 = l & 31, lh = l >> 5;
  const int wr = w >> 3, wc = w & 7;
  const int b = blockIdx.y, m0 = blockIdx.x * 64;
  float* __restrict__ hb = hio + ((size_t)b * NN + m0) * HH;
  const f16* __restrict__ h16b = HF ? (h16 + ((size_t)b * NN + m0) * HH) : nullptr;

  const int myrow = wr * 32 + l31;       // A-frag row (0..63)
  f32x16 Oacc[4] = {};                   // rows wr*32+pat, cols wc*128+ht*32+l31

  for (int ft = 0; ft < 16; ++ft) {
    const int f0 = ft * 256;
    f32x16 sacc = {};

    // ---- mm1: u = h @ w1t[f-tile]^T, K-chunks of 64, dbuf ----
    stageW1(REG, w1t, f0, 0, w, l);
    f16x8 ah[4];
#pragma unroll
    for (int s = 0; s < 4; ++s) {
      if (HF) ah[s] = *(const f16x8*)(h16b + (size_t)myrow * HH + s * 16 + lh * 8);
      else    ah[s] = cvt8(hb + (size_t)myrow * HH + s * 16 + lh * 8);
    }
    __syncthreads();
    int buf = 0;
    for (int kc = 0; kc < 16; ++kc) {
      f16x8 na[4];
      if (kc < 15) {
        const int kn = (kc + 1) * 64;
        stageW1(REG + (buf ^ 1) * 32768, w1t, f0, kn, w, l);
#pragma unroll
        for (int s = 0; s < 4; ++s) {
          if (HF) na[s] = *(const f16x8*)(h16b + (size_t)myrow * HH + kn + s * 16 + lh * 8);
          else    na[s] = cvt8(hb + (size_t)myrow * HH + kn + s * 16 + lh * 8);
        }
      }
      const char* W = REG + buf * 32768;
      const int j = wc * 32 + l31;            // f row
      const char* rb = W + j * 128;
      const int key = j & 7;
#pragma unroll
      for (int s = 0; s < 4; ++s) {
        const int p = (s * 2 + lh) ^ key;
        f16x8 bf = *(const f16x8*)(rb + p * 16);
        sacc = MFMA32(ah[s], bf, sacc);
      }
      __syncthreads();
      if (kc < 15) {
#pragma unroll
        for (int s = 0; s < 4; ++s) ah[s] = na[s];
      }
      buf ^= 1;
    }

    // ---- bias + GELU -> GB (swizzled [64][256] f16) ----
    {
      const int fcol = wc * 32 + l31;
      const float b1v = b1f[f0 + fcol];
#pragma unroll
      for (int rg = 0; rg < 16; ++rg) {
        float g = gelu(sacc[rg] + b1v);
        float go = __shfl_xor(g, 1, 64);
        if (!(l & 1)) {
          const int row = wr * 32 + (rg & 3) + 8 * (rg >> 2) + 4 * lh;
          const int s = fcol >> 3;
          const int p = s ^ (row & 31);
          *(unsigned*)(GB + row * 512 + p * 16 + (fcol & 7) * 2) = pack2(g, go);
        }
      }
    }
    __syncthreads();

    // ---- mm2: Oacc += g @ w2t[f-tile], f-chunks of 16, dbuf ----
    stageW2(REG, w2t, f0, w, l);
    __syncthreads();
    int vb_ = 0;
    for (int fc = 0; fc < 16; ++fc) {
      if (fc < 15) stageW2(REG + (vb_ ^ 1) * 32768, w2t, f0 + (fc + 1) * 16, w, l);
      const char* Vc = REG + vb_ * 32768;
      const int ps = (fc * 2 + lh) ^ (myrow & 31);
      f16x8 pa = *(const f16x8*)(GB + myrow * 512 + ps * 16);
#pragma unroll
      for (int ht = 0; ht < 4; ++ht) {
        const int h = wc * 128 + ht * 32 + l31;
        f16x8 vb = *(const f16x8*)(Vc + h * 32 + ((lh ^ ((h >> 2) & 1)) * 16));
        Oacc[ht] = MFMA32(pa, vb, Oacc[ht]);
      }
      __syncthreads();
      vb_ ^= 1;
    }
  }

  // ---- epilogue: y = h + ffn + b2 ; LN2 ; write in place ----
  float musum[16];
#pragma unroll
  for (int rg = 0; rg < 16; ++rg) musum[rg] = 0.f;
#pragma unroll
  for (int ht = 0; ht < 4; ++ht) {
    const int col = wc * 128 + ht * 32 + l31;
    const float b2v = b2f[col];
#pragma unroll
    for (int rg = 0; rg < 16; ++rg) {
      const int row = wr * 32 + (rg & 3) + 8 * (rg >> 2) + 4 * lh;
      float v = hb[(size_t)row * HH + col] + Oacc[ht][rg] + b2v;
      Oacc[ht][rg] = v; musum[rg] += v;
    }
  }
#pragma unroll
  for (int off = 1; off <= 16; off <<= 1)
#pragma unroll
    for (int rg = 0; rg < 16; ++rg) musum[rg] += __shfl_xor(musum[rg], off, 64);
  if (l31 == 0) {
#pragma unroll
    for (int rg = 0; rg < 16; ++rg) {
      const int rl = (rg & 3) + 8 * (rg >> 2) + 4 * lh;
      RD[wc * 64 + wr * 32 + rl] = musum[rg];
    }
  }
  __syncthreads();
  if (t < 64) {
    float s = 0.f;
#pragma unroll
    for (int q = 0; q < 8; ++q) s += RD[q * 64 + t];
    MUB[t] = s * (1.0f / HH);
  }
  __syncthreads();
  float mu[16], vsum[16];
#pragma unroll
  for (int rg = 0; rg < 16; ++rg) {
    mu[rg] = MUB[wr * 32 + (rg & 3) + 8 * (rg >> 2) + 4 * lh];
    vsum[rg] = 0.f;
  }
#pragma unroll
  for (int ht = 0; ht < 4; ++ht)
#pragma unroll
    for (int rg = 0; rg < 16; ++rg) {
      float d = Oacc[ht][rg] - mu[rg];
      vsum[rg] += d * d;
    }
#pragma unroll
  for (int off = 1; off <= 16; off <<= 1)
#pragma unroll
    for (int rg = 0; rg < 16; ++rg) vsum[rg] += __shfl_xor(vsum[rg], off, 64);
  if (l31 == 0) {
#pragma unroll
    for (int rg = 0; rg < 16; ++rg) {
      const int rl = (rg & 3) + 8 * (rg >> 2) + 4 * lh;
      RD[wc * 64 + wr * 32 + rl] = vsum[rg];
    }
  }
  __syncthreads();
  if (t < 64) {
    float s = 0.f;
#pragma unroll
    for (int q = 0; q < 8; ++q) s += RD[q * 64 + t];
    RSB[t] = rsqrtf(s * (1.0f / HH) + EPS_);
  }
  __syncthreads();
  float rs[16];
#pragma unroll
  for (int rg = 0; rg < 16; ++rg)
    rs[rg] = RSB[wr * 32 + (rg & 3) + 8 * (rg >> 2) + 4 * lh];
#pragma unroll
  for (int ht = 0; ht < 4; ++ht) {
    const int col = wc * 128 + ht * 32 + l31;
    const float gv = g2[col], bv = lb2[col];
#pragma unroll
    for (int rg = 0; rg < 16; ++rg) {
      const int row = wr * 32 + (rg & 3) + 8 * (rg >> 2) + 4 * lh;
      hb[(size_t)row * HH + col] = (Oacc[ht][rg] - mu[rg]) * rs[rg] * gv + bv;
    }
  }
}

// ---------------- legacy attn (fallback when ws < 112 MB) ----------------
__global__ __launch_bounds__(1024)
void attn_legacy(const float* __restrict__ x, const float* __restrict__ g1,
                 const float* __restrict__ lb1, float* __restrict__ hout) {
  extern __shared__ char smem[];
  char* AB = smem;
  char* BB = smem + 5120;
  char* PB2 = smem + 46080;
  char* VB = smem + 62976;
  float* RD  = (float*)(smem + 144896);
  float* RD2 = (float*)(smem + 145920);

  const int t = threadIdx.x, l = t & 63, w = t >> 6;
  const int lg = l >> 4, li = l & 15;
  const int wr = w >> 3, wc = w & 7;
  const int b = blockIdx.y, m0 = blockIdx.x * 32;
  const float* __restrict__ xb = x + (size_t)b * NN * HH;

  const int ar = t >> 5, ak = t & 31;
  const int bj = t >> 2, bq = t & 3;
  const int vjp = t & 15, vhg = t >> 4;

  f32x4 Oacc[8] = {};
  float m_run[4] = {-INFINITY, -INFINITY, -INFINITY, -INFINITY};
  float l_run[4] = {0.f, 0.f, 0.f, 0.f};

  for (int jt = 0; jt < 8; ++jt) {
    const int j0 = jt * 256;
    f32x4 sacc[2] = {};
    float qv = xb[(size_t)(m0 + ar) * HH + ak];
    float4 ca = ld4(xb + (size_t)(j0 + bj) * HH + bq * 8);
    float4 cb = ld4(xb + (size_t)(j0 + bj) * HH + bq * 8 + 4);
    for (int kc = 0; kc < 32; ++kc) {
      __syncthreads();
      {
        f16 qh = (f16)qv; f16 ql = (f16)(qv - (float)qh);
        *(ushort*)(AB + ar * 80 + ak * 2) = h2u(qh);
        *(ushort*)(AB + 2560 + ar * 80 + ak * 2) = h2u(ql);
        float vv[8] = {ca.x, ca.y, ca.z, ca.w, cb.x, cb.y, cb.z, cb.w};
        f16x8 hi8, lo8;
#pragma unroll
        for (int i = 0; i < 8; ++i) {
          f16 h = (f16)vv[i]; hi8[i] = h; lo8[i] = (f16)(vv[i] - (float)h);
        }
        *(f16x8*)(BB + bj * 80 + bq * 16) = hi8;
        *(f16x8*)(BB + 20480 + bj * 80 + bq * 16) = lo8;
      }
      if (kc < 31) {
        const int k0 = (kc + 1) * 32;
        qv = xb[(size_t)(m0 + ar) * HH + k0 + ak];
        ca = ld4(xb + (size_t)(j0 + bj) * HH + k0 + bq * 8);
        cb = ld4(xb + (size_t)(j0 + bj) * HH + k0 + bq * 8 + 4);
      }
      __syncthreads();
      const int arow = wr * 16 + li;
      f16x8 ahi = *(const f16x8*)(AB + arow * 80 + lg * 16);
      f16x8 alo = *(const f16x8*)(AB + 2560 + arow * 80 + lg * 16);
#pragma unroll
      for (int ct = 0; ct < 2; ++ct) {
        const int j = wc * 32 + ct * 16 + li;
        f16x8 bhi = *(const f16x8*)(BB + j * 80 + lg * 16);
        f16x8 blo = *(const f16x8*)(BB + 20480 + j * 80 + lg * 16);
        sacc[ct] = MFMA16(ahi, bhi, sacc[ct]);
        sacc[ct] = MFMA16(ahi, blo, sacc[ct]);
        sacc[ct] = MFMA16(alo, bhi, sacc[ct]);
      }
    }
    float m[4];
#pragma unroll
    for (int r = 0; r < 4; ++r) m[r] = fmaxf(sacc[0][r], sacc[1][r]);
#pragma unroll
    for (int off = 1; off <= 8; off <<= 1)
#pragma unroll
      for (int r = 0; r < 4; ++r) m[r] = fmaxf(m[r], __shfl_xor(m[r], off, 64));
    if (li == 0)
#pragma unroll
      for (int r = 0; r < 4; ++r) RD[wc * 32 + wr * 16 + lg * 4 + r] = m[r];
    __syncthreads();
    float mnew[4], fct[4];
#pragma unroll
    for (int r = 0; r < 4; ++r) {
      const int row = wr * 16 + lg * 4 + r;
      float mt = RD[row];
#pragma unroll
      for (int w2 = 1; w2 < 8; ++w2) mt = fmaxf(mt, RD[w2 * 32 + row]);
      mnew[r] = fmaxf(m_run[r], mt);
      fct[r] = __expf(m_run[r] - mnew[r]);
      m_run[r] = mnew[r];
    }
    float psum[4] = {0.f, 0.f, 0.f, 0.f};
#pragma unroll
    for (int ct = 0; ct < 2; ++ct)
#pragma unroll
      for (int r = 0; r < 4; ++r) {
        float p = __expf(sacc[ct][r] - mnew[r]);
        psum[r] += p;
        float po = __shfl_xor(p, 1, 64);
        if (!(l & 1)) {
          const int row = wr * 16 + lg * 4 + r;
          *(unsigned*)(PB2 + row * 528 + (wc * 32 + ct * 16 + (li & 14)) * 2) = pack2(p, po);
        }
      }
#pragma unroll
    for (int off = 1; off <= 8; off <<= 1)
#pragma unroll
      for (int r = 0; r < 4; ++r) psum[r] += __shfl_xor(psum[r], off, 64);
    if (li == 0)
#pragma unroll
      for (int r = 0; r < 4; ++r) RD2[wc * 32 + wr * 16 + lg * 4 + r] = psum[r];
    __syncthreads();
#pragma unroll
    for (int r = 0; r < 4; ++r) {
      const int row = wr * 16 + lg * 4 + r;
      float ts = 0.f;
#pragma unroll
      for (int w2 = 0; w2 < 8; ++w2) ts += RD2[w2 * 32 + row];
      l_run[r] = l_run[r] * fct[r] + ts;
    }
#pragma unroll
    for (int ti = 0; ti < 8; ++ti)
#pragma unroll
      for (int r = 0; r < 4; ++r) Oacc[ti][r] *= fct[r];

    float4 v0[4], v1[4];
#pragma unroll
    for (int q = 0; q < 4; ++q) {
      v0[q] = ld4(xb + (size_t)(j0 + 2 * vjp) * HH + vhg * 16 + q * 4);
      v1[q] = ld4(xb + (size_t)(j0 + 2 * vjp + 1) * HH + vhg * 16 + q * 4);
    }
    for (int jc = 0; jc < 8; ++jc) {
      __syncthreads();
#pragma unroll
      for (int q = 0; q < 4; ++q) {
        float a0[4] = {v0[q].x, v0[q].y, v0[q].z, v0[q].w};
        float a1[4] = {v1[q].x, v1[q].y, v1[q].z, v1[q].w};
#pragma unroll
        for (int i = 0; i < 4; ++i) {
          const int h = vhg * 16 + q * 4 + i;
          *(unsigned*)(VB + h * 80 + vjp * 4) = pack2(a0[i], a1[i]);
        }
      }
      if (jc < 7) {
        const int jj = j0 + (jc + 1) * 32;
#pragma unroll
        for (int q = 0; q < 4; ++q) {
          v0[q] = ld4(xb + (size_t)(jj + 2 * vjp) * HH + vhg * 16 + q * 4);
          v1[q] = ld4(xb + (size_t)(jj + 2 * vjp + 1) * HH + vhg * 16 + q * 4);
        }
      }
      __syncthreads();
      f16x8 pa = *(const f16x8*)(PB2 + (wr * 16 + li) * 528 + jc * 64 + lg * 16);
#pragma unroll
      for (int ti = 0; ti < 8; ++ti) {
        const int h = wc * 128 + ti * 16 + li;
        f16x8 vb = *(const f16x8*)(VB + h * 80 + lg * 16);
        Oacc[ti] = MFMA16(pa, vb, Oacc[ti]);
      }
    }
  }

  float musum[4] = {0.f, 0.f, 0.f, 0.f};
#pragma unroll
  for (int ti = 0; ti < 8; ++ti) {
    const int col = wc * 128 + ti * 16 + li;
#pragma unroll
    for (int r = 0; r < 4; ++r) {
      const int row = m0 + wr * 16 + lg * 4 + r;
      float v = xb[(size_t)row * HH + col] + Oacc[ti][r] / l_run[r];
      Oacc[ti][r] = v; musum[r] += v;
    }
  }
#pragma unroll
  for (int off = 1; off <= 8; off <<= 1)
#pragma unroll
    for (int r = 0; r < 4; ++r) musum[r] += __shfl_xor(musum[r], off, 64);
  if (li == 0)
#pragma unroll
    for (int r = 0; r < 4; ++r) RD[wc * 32 + wr * 16 + lg * 4 + r] = musum[r];
  __syncthreads();
  float mu[4];
#pragma unroll
  for (int r = 0; r < 4; ++r) {
    const int row = wr * 16 + lg * 4 + r;
    float s = 0.f;
#pragma unroll
    for (int w2 = 0; w2 < 8; ++w2) s += RD[w2 * 32 + row];
    mu[r] = s * (1.0f / HH);
  }
  float vsum[4] = {0.f, 0.f, 0.f, 0.f};
#pragma unroll
  for (int ti = 0; ti < 8; ++ti)
#pragma unroll
    for (int r = 0; r < 4; ++r) {
      float d = Oacc[ti][r] - mu[r]; vsum[r] += d * d;
    }
#pragma unroll
  for (int off = 1; off <= 8; off <<= 1)
#pragma unroll
    for (int r = 0; r < 4; ++r) vsum[r] += __shfl_xor(vsum[r], off, 64);
  if (li == 0)
#pragma unroll
    for (int r = 0; r < 4; ++r) RD2[wc * 32 + wr * 16 + lg * 4 + r] = vsum[r];
  __syncthreads();
  float rs[4];
#pragma unroll
  for (int r = 0; r < 4; ++r) {
    const int row = wr * 16 + lg * 4 + r;
    float s = 0.f;
#pragma unroll
    for (int w2 = 0; w2 < 8; ++w2) s += RD2[w2 * 32 + row];
    rs[r] = rsqrtf(s * (1.0f / HH) + EPS_);
  }
#pragma unroll
  for (int ti = 0; ti < 8; ++ti) {
    const int col = wc * 128 + ti * 16 + li;
    const float gv = g1[col], bv = lb1[col];
#pragma unroll
    for (int r = 0; r < 4; ++r) {
      const int row = m0 + wr * 16 + lg * 4 + r;
      hout[((size_t)b * NN + row) * HH + col] = (Oacc[ti][r] - mu[r]) * rs[r] * gv + bv;
    }
  }
}

// ---------------- legacy ffn (fallback when ws < 16 MB; fp32 weights) ----------------
__global__ __launch_bounds__(1024)
void ffn_legacy(float* __restrict__ hio, const float* __restrict__ g2,
                const float* __restrict__ lb2,
                const float* __restrict__ w1, const float* __restrict__ b1f,
                const float* __restrict__ w2, const float* __restrict__ b2f) {
  extern __shared__ char smem[];
  char* HB  = smem;
  char* W1B = smem + 5120;
  char* GB  = smem + 25600;
  char* W2B = smem + 59392;
  float* RD  = (float*)(smem + 141312);
  float* RD2 = (float*)(smem + 142336);

  const int t = threadIdx.x, l = t & 63;
  const int w = t >> 6;
  const int lg = l >> 4, li = l & 15;
  const int rt = w >> 2, wc4 = w & 3;
  const int b = blockIdx.y, m0 = blockIdx.x * 64;
  float* __restrict__ hb = hio + ((size_t)b * NN + m0) * HH;

  f32x4 Oacc[16] = {};

  for (int ft = 0; ft < 16; ++ft) {
    const int f0 = ft * 256;
    f32x4 uacc[4] = {};
    const int hr = t >> 4, hk2 = t & 15;
    float2 hv = *(const float2*)(hb + (size_t)hr * HH + hk2 * 2);
    float4 wf0, wf1;
    const int ki = t & 31, fg = t >> 5;
    wf0 = ld4(w1 + (size_t)ki * FFD + f0 + fg * 8);
    wf1 = ld4(w1 + (size_t)ki * FFD + f0 + fg * 8 + 4);
    for (int kc = 0; kc < 32; ++kc) {
      __syncthreads();
      *(unsigned*)(HB + hr * 80 + hk2 * 4) = pack2(hv.x, hv.y);
      {
        float vv[8] = {wf0.x, wf0.y, wf0.z, wf0.w, wf1.x, wf1.y, wf1.z, wf1.w};
#pragma unroll
        for (int i = 0; i < 8; ++i)
          *(ushort*)(W1B + (fg * 8 + i) * 80 + ki * 2) = h2u((f16)vv[i]);
      }
      if (kc < 31) {
        const int k0 = (kc + 1) * 32;
        hv = *(const float2*)(hb + (size_t)hr * HH + k0 + hk2 * 2);
        wf0 = ld4(w1 + (size_t)(k0 + ki) * FFD + f0 + fg * 8);
        wf1 = ld4(w1 + (size_t)(k0 + ki) * FFD + f0 + fg * 8 + 4);
      }
      __syncthreads();
      f16x8 af = *(const f16x8*)(HB + (rt * 16 + li) * 80 + lg * 16);
#pragma unroll
      for (int ct = 0; ct < 4; ++ct) {
        const int fc = wc4 * 64 + ct * 16 + li;
        f16x8 bf = *(const f16x8*)(W1B + fc * 80 + lg * 16);
        uacc[ct] = MFMA16(af, bf, uacc[ct]);
      }
    }
    __syncthreads();
#pragma unroll
    for (int ct = 0; ct < 4; ++ct) {
      const int ucol = wc4 * 64 + ct * 16 + li;
      const float b1v = b1f[f0 + ucol];
#pragma unroll
      for (int r = 0; r < 4; ++r) {
        float g = gelu(uacc[ct][r] + b1v);
        float go = __shfl_xor(g, 1, 64);
        if (!(l & 1)) {
          const int row = rt * 16 + lg * 4 + r;
          *(unsigned*)(GB + row * 528 + (wc4 * 64 + ct * 16 + (li & 14)) * 2) = pack2(g, go);
        }
      }
    }
    __syncthreads();
    float4 fv[8];
    const int w2fi = t & 31, w2hg = t >> 5;
#pragma unroll
    for (int q = 0; q < 8; ++q)
      fv[q] = ld4(w2 + (size_t)(f0 + w2fi) * HH + w2hg * 32 + q * 4);
    for (int fc = 0; fc < 8; ++fc) {
#pragma unroll
      for (int q = 0; q < 8; ++q) {
        float vv[4] = {fv[q].x, fv[q].y, fv[q].z, fv[q].w};
#pragma unroll
        for (int i = 0; i < 4; ++i)
          *(ushort*)(W2B + (w2hg * 32 + q * 4 + i) * 80 + w2fi * 2) = h2u((f16)vv[i]);
      }
      if (fc < 7) {
        const int fk = f0 + (fc + 1) * 32;
#pragma unroll
        for (int q = 0; q < 8; ++q)
          fv[q] = ld4(w2 + (size_t)(fk + w2fi) * HH + w2hg * 32 + q * 4);
      }
      __syncthreads();
      f16x8 ag = *(const f16x8*)(GB + (rt * 16 + li) * 528 + fc * 64 + lg * 16);
#pragma unroll
      for (int ti = 0; ti < 16; ++ti) {
        const int h = wc4 * 256 + ti * 16 + li;
        f16x8 bg = *(const f16x8*)(W2B + h * 80 + lg * 16);
        Oacc[ti] = MFMA16(ag, bg, Oacc[ti]);
      }
      __syncthreads();
    }
  }

  float musum[4] = {0.f, 0.f, 0.f, 0.f};
#pragma unroll
  for (int ti = 0; ti < 16; ++ti) {
    const int col = wc4 * 256 + ti * 16 + li;
    const float b2v = b2f[col];
#pragma unroll
    for (int r = 0; r < 4; ++r) {
      const int row = rt * 16 + lg * 4 + r;
      float v = hb[(size_t)row * HH + col] + Oacc[ti][r] + b2v;
      Oacc[ti][r] = v; musum[r] += v;
    }
  }
#pragma unroll
  for (int off = 1; off <= 8; off <<= 1)
#pragma unroll
    for (int r = 0; r < 4; ++r) musum[r] += __shfl_xor(musum[r], off, 64);
  if (li == 0)
#pragma unroll
    for (int r = 0; r < 4; ++r) RD[wc4 * 64 + rt * 16 + lg * 4 + r] = musum[r];
  __syncthreads();
  float mu[4];
#pragma unroll
  for (int r = 0; r < 4; ++r) {
    const int row = rt * 16 + lg * 4 + r;
    float s = 0.f;
#pragma unroll
    for (int w2i = 0; w2i < 4; ++w2i) s += RD[w2i * 64 + row];
    mu[r] = s * (1.0f / HH);
  }
  float vsum[4] = {0.f, 0.f, 0.f, 0.f};
#pragma unroll
  for (int ti = 0; ti < 16; ++ti)
#pragma unroll
    for (int r = 0; r < 4; ++r) { float d = Oacc[ti][r] - mu[r]; vsum[r] += d * d; }
#pragma unroll
  for (int off = 1; off <= 8; off <<= 1)
#pragma unroll
    for (int r = 0; r < 4; ++r) vsum[r] += __shfl_xor(vsum[r], off, 64);
  if (li == 0)
#pragma unroll
    for (int r = 0; r < 4; ++r) RD2[wc4 * 64 + rt * 16 + lg * 4 + r] = vsum[r];
  __syncthreads();
  float rs[4];
#pragma unroll
  for (int r = 0; r < 4; ++r) {
    const int row = rt * 16 + lg * 4 + r;
    float s = 0.f;
#pragma unroll
    for (int w2i = 0; w2i < 4; ++w2i) s += RD2[w2i * 64 + row];
    rs[r] = rsqrtf(s * (1.0f / HH) + EPS_);
  }
#pragma unroll
  for (int ti = 0; ti < 16; ++ti) {
    const int col = wc4 * 256 + ti * 16 + li;
    const float gv = g2[col], bv = lb2[col];
#pragma unroll
    for (int r = 0; r < 4; ++r) {
      const int row = rt * 16 + lg * 4 + r;
      hb[(size_t)row * HH + col] = (Oacc[ti][r] - mu[r]) * rs[r] * gv + bv;
    }
  }
}

extern "C" void kernel_launch(void* const* d_in, const int* in_sizes, int n_in,
                              void* d_out, int out_size, void* d_ws, size_t ws_size,
                              hipStream_t stream) {
  (void)in_sizes; (void)n_in; (void)out_size;
  const float* x    = (const float*)d_in[0];
  const float* ln1g = (const float*)d_in[1];
  const float* ln1b = (const float*)d_in[2];
  const float* ln2g = (const float*)d_in[3];
  const float* ln2b = (const float*)d_in[4];
  const float* w1   = (const float*)d_in[5];
  const float* bb1  = (const float*)d_in[6];
  const float* w2   = (const float*)d_in[7];
  const float* bb2  = (const float*)d_in[8];
  float* out = (float*)d_out;

  const size_t wN = (size_t)FFD * HH;
  const size_t xN = (size_t)NB * NN * HH;
  const size_t need_w    = 2 * wN * sizeof(f16);              // 16 MiB
  const size_t need_attn = need_w + 3 * xN * sizeof(f16);     // 112 MiB
  const size_t need_h16  = need_attn + xN * sizeof(f16);      // 144 MiB
  const bool ws_w    = (ws_size >= need_w) && d_ws;
  const bool ws_attn = (ws_size >= need_attn) && d_ws;
  const bool ws_h16  = (ws_size >= need_h16) && d_ws;

  f16* w1t = (f16*)d_ws;
  f16* w2t = w1t + wN;
  f16* xh  = w2t + wN;
  f16* xl  = xh + xN;
  f16* xt  = xl + xN;
  f16* h16 = xt + xN;

  (void)hipFuncSetAttribute((const void*)attn_v2<true>,
                            hipFuncAttributeMaxDynamicSharedMemorySize, 101376);
  (void)hipFuncSetAttribute((const void*)attn_v2<false>,
                            hipFuncAttributeMaxDynamicSharedMemorySize, 101376);
  (void)hipFuncSetAttribute((const void*)attn_legacy,
                            hipFuncAttributeMaxDynamicSharedMemorySize, 146944);
  (void)hipFuncSetAttribute((const void*)ffn_v2<true>,
                            hipFuncAttributeMaxDynamicSharedMemorySize, 100864);
  (void)hipFuncSetAttribute((const void*)ffn_v2<false>,
                            hipFuncAttributeMaxDynamicSharedMemorySize, 100864);
  (void)hipFuncSetAttribute((const void*)ffn_legacy,
                            hipFuncAttributeMaxDynamicSharedMemorySize, 143360);

  if (ws_w) {
    transpose_f16k<<<dim3(FFD / 32, HH / 32, 1), 256, 0, stream>>>(w1, w1t, HH, FFD, 0, 0);
    transpose_f16k<<<dim3(HH / 32, FFD / 32, 1), 256, 0, stream>>>(w2, w2t, FFD, HH, 0, 0);
  }
  if (ws_attn) {
    convert_hl<<<(int)(xN / 4 / 256), 256, 0, stream>>>(x, xh, xl);
    transpose_f16k<<<dim3(HH / 32, NN / 32, NB), 256, 0, stream>>>(
        x, xt, NN, HH, (long)NN * HH, (long)HH * NN);
    if (ws_h16)
      attn_v2<true><<<dim3(NN / 64, NB), 512, 101376, stream>>>(
          x, xh, xl, xt, ln1g, ln1b, out, h16);
    else
      attn_v2<false><<<dim3(NN / 64, NB), 512, 101376, stream>>>(
          x, xh, xl, xt, ln1g, ln1b, out, nullptr);
  } else {
    attn_legacy<<<dim3(NN / 32, NB), 1024, 146944, stream>>>(x, ln1g, ln1b, out);
  }
  if (ws_w) {
    if (ws_h16)
      ffn_v2<true><<<dim3(NN / 64, NB), 1024, 100864, stream>>>(
          out, h16, ln2g, ln2b, bb1, bb2, w1t, w2t);
    else
      ffn_v2<false><<<dim3(NN / 64, NB), 1024, 100864, stream>>>(
          out, nullptr, ln2g, ln2b, bb1, bb2, w1t, w2t);
  } else {
    ffn_legacy<<<dim3(NN / 64, NB), 1024, 143360, stream>>>(
        out, ln2g, ln2b, w1, bb1, w2, bb2);
  }
}